// Round 4
// baseline (298.398 us; speedup 1.0000x reference)
//
#include <hip/hip_runtime.h>

// MaxUnpooling2D scatter-add: out[mask[i]] += updates[i]
//   n = 8,388,608 updates (fp32) + indices (int32), out_size = 33,554,432 fp32 (134 MB).
//
// v4: partition (block-local counting sort, coalesced pair dump) unchanged.
//     + table transpose so unbin's descriptor read is coalesced.
//     + unbin rewritten as cooperative work-list gather: block-scan of chunk
//       counts, flat item loop with lane-consecutive pair addresses (line-sized
//       runs), 10-step LDS binary search for chunk lookup, ds_add_f32 into the
//       64 KB tile, coalesced float4 tile store (no zero pass on d_out).

#define NB        2048          // buckets; bucket = idx >> 14
#define NB_SHIFT  14
#define RB        16384         // floats per bucket output region (64 KB)
#define P1B       1024          // partition blocks
#define IPB       8192          // items per partition block (= n / P1B)

__global__ __launch_bounds__(256) void partition_kernel(
        const float4* __restrict__ upd4,
        const int4*   __restrict__ mask4,
        unsigned int* __restrict__ tableA,   // [P1B][NB] packed: start | cnt<<16
        uint2*        __restrict__ pairs) {  // [P1B][IPB]
    __shared__ unsigned int hb[NB];      // hist -> base/cursor
    __shared__ unsigned int tsum[256];
    __shared__ uint2 stage[IPB];         // 64 KB
    const int t = threadIdx.x;
    const int k = blockIdx.x;
    const int s4 = k * (IPB / 4);

    for (int b = t; b < NB; b += 256) hb[b] = 0u;
    __syncthreads();

    int4 mm[IPB / 4 / 256];
    #pragma unroll
    for (int j = 0; j < IPB / 4 / 256; ++j) mm[j] = mask4[s4 + j * 256 + t];
    #pragma unroll
    for (int j = 0; j < IPB / 4 / 256; ++j) {
        atomicAdd(&hb[((unsigned)mm[j].x) >> NB_SHIFT], 1u);
        atomicAdd(&hb[((unsigned)mm[j].y) >> NB_SHIFT], 1u);
        atomicAdd(&hb[((unsigned)mm[j].z) >> NB_SHIFT], 1u);
        atomicAdd(&hb[((unsigned)mm[j].w) >> NB_SHIFT], 1u);
    }
    __syncthreads();

    // Block-wide exclusive scan of hb[NB]
    unsigned c[8], s = 0;
    #pragma unroll
    for (int j = 0; j < 8; ++j) { c[j] = hb[t * 8 + j]; s += c[j]; }
    tsum[t] = s;
    __syncthreads();
    #pragma unroll
    for (int d = 1; d < 256; d <<= 1) {
        unsigned v = (t >= d) ? tsum[t - d] : 0u;
        __syncthreads();
        tsum[t] += v;
        __syncthreads();
    }
    unsigned run = (t > 0) ? tsum[t - 1] : 0u;
    #pragma unroll
    for (int j = 0; j < 8; ++j) {
        unsigned b = t * 8 + j;
        hb[b] = run;
        tableA[(size_t)k * NB + b] = run | (c[j] << 16);
        run += c[j];
    }
    __syncthreads();

    float4 uu[IPB / 4 / 256];
    #pragma unroll
    for (int j = 0; j < IPB / 4 / 256; ++j) uu[j] = upd4[s4 + j * 256 + t];
    #pragma unroll
    for (int j = 0; j < IPB / 4 / 256; ++j) {
        #define PLACE(mi, vi) { \
            unsigned b_ = ((unsigned)(mi)) >> NB_SHIFT; \
            unsigned pos_ = atomicAdd(&hb[b_], 1u); \
            stage[pos_] = make_uint2(((unsigned)(mi)) & (RB - 1u), __float_as_uint(vi)); }
        PLACE(mm[j].x, uu[j].x)
        PLACE(mm[j].y, uu[j].y)
        PLACE(mm[j].z, uu[j].z)
        PLACE(mm[j].w, uu[j].w)
        #undef PLACE
    }
    __syncthreads();

    const uint4* sp = (const uint4*)stage;
    uint4* dp = (uint4*)(pairs + (size_t)k * IPB);
    #pragma unroll
    for (int j = 0; j < IPB / 2 / 256; ++j) dp[j * 256 + t] = sp[j * 256 + t];
}

// tableA [P1B][NB] -> tableB [NB][P1B] so unbin reads its row coalesced.
__global__ __launch_bounds__(256) void transpose_kernel(
        const unsigned int* __restrict__ A, unsigned int* __restrict__ B) {
    __shared__ unsigned int tile[32][33];
    const int tx = threadIdx.x & 31, ty = threadIdx.x >> 5;
    const int bx = blockIdx.x;   // 64 tiles along NB
    const int by = blockIdx.y;   // 32 tiles along P1B
    #pragma unroll
    for (int r = 0; r < 32; r += 8)
        tile[ty + r][tx] = A[(size_t)(by * 32 + ty + r) * NB + bx * 32 + tx];
    __syncthreads();
    #pragma unroll
    for (int r = 0; r < 32; r += 8)
        B[(size_t)(bx * 32 + ty + r) * P1B + by * 32 + tx] = tile[tx][ty + r];
}

__global__ __launch_bounds__(256) void unbin_kernel(
        const unsigned int* __restrict__ tableB,  // [NB][P1B]
        const uint2*        __restrict__ pairs,
        float4*             __restrict__ out4) {
    extern __shared__ float tile[];     // RB floats = 64 KB (dynamic)
    __shared__ unsigned choff[P1B];     // exclusive prefix of chunk counts
    __shared__ unsigned chbase[P1B];    // global pair index base per chunk
    __shared__ unsigned wpart[4];
    __shared__ unsigned Ttot;
    const int b = blockIdx.x, t = threadIdx.x;
    float4* t4 = (float4*)tile;

    for (int j = t; j < RB / 4; j += 256) t4[j] = make_float4(0.f, 0.f, 0.f, 0.f);

    // Coalesced descriptor read: 4 chunks per thread
    uint4 e = ((const uint4*)(tableB + (size_t)b * P1B))[t];
    unsigned c0 = e.x >> 16, c1 = e.y >> 16, c2 = e.z >> 16, c3 = e.w >> 16;
    unsigned s = c0 + c1 + c2 + c3;

    // wave-inclusive scan over 64 lanes, then cross-wave
    unsigned inc = s;
    #pragma unroll
    for (int d = 1; d < 64; d <<= 1) {
        unsigned v = __shfl_up(inc, d, 64);
        if ((t & 63) >= d) inc += v;
    }
    if ((t & 63) == 63) wpart[t >> 6] = inc;
    __syncthreads();
    unsigned wbase = 0;
    #pragma unroll
    for (int w = 0; w < 4; ++w) if (w < (t >> 6)) wbase += wpart[w];
    unsigned ex = wbase + inc - s;     // exclusive prefix for this thread's 4 chunks

    const unsigned k0 = t * 4;
    choff[k0 + 0] = ex;                 chbase[k0 + 0] = (k0 + 0) * IPB + (e.x & 0xFFFFu);
    choff[k0 + 1] = ex + c0;            chbase[k0 + 1] = (k0 + 1) * IPB + (e.y & 0xFFFFu);
    choff[k0 + 2] = ex + c0 + c1;       chbase[k0 + 2] = (k0 + 2) * IPB + (e.z & 0xFFFFu);
    choff[k0 + 3] = ex + c0 + c1 + c2;  chbase[k0 + 3] = (k0 + 3) * IPB + (e.w & 0xFFFFu);
    if (t == 255) Ttot = ex + s;
    __syncthreads();   // tile zeroed + choff/chbase/Ttot visible

    const unsigned T = Ttot;
    for (unsigned i = t; i < T; i += 256) {
        unsigned k = 0;                      // max k with choff[k] <= i (choff[0]=0)
        #pragma unroll
        for (unsigned stp = 512; stp; stp >>= 1) {
            unsigned nk = k + stp;
            if (nk < P1B && choff[nk] <= i) k = nk;
        }
        uint2 pr = pairs[chbase[k] + (i - choff[k])];
        atomicAdd(&tile[pr.x], __uint_as_float(pr.y));
    }
    __syncthreads();

    for (int j = t; j < RB / 4; j += 256)
        out4[(size_t)b * (RB / 4) + j] = t4[j];
}

// ---- fallback (direct atomics) if workspace/shape unexpected ----
__global__ void zero_out_kernel(float4* __restrict__ out, int n4) {
    int i = blockIdx.x * blockDim.x + threadIdx.x;
    if (i < n4) out[i] = make_float4(0.f, 0.f, 0.f, 0.f);
}
__global__ void scatter_add_kernel(const float4* __restrict__ upd,
                                   const int4* __restrict__ mask,
                                   float* __restrict__ out, int n4) {
    int i = blockIdx.x * blockDim.x + threadIdx.x;
    if (i < n4) {
        float4 u = upd[i];
        int4 m = mask[i];
        atomicAdd(out + m.x, u.x);
        atomicAdd(out + m.y, u.y);
        atomicAdd(out + m.z, u.z);
        atomicAdd(out + m.w, u.w);
    }
}

extern "C" void kernel_launch(void* const* d_in, const int* in_sizes, int n_in,
                              void* d_out, int out_size, void* d_ws, size_t ws_size,
                              hipStream_t stream) {
    const float* updates = (const float*)d_in[0];
    const int*   mask    = (const int*)d_in[1];
    float* out = (float*)d_out;
    const int n  = in_sizes[0];          // 8,388,608
    const int n4 = n >> 2;
    const int o4 = out_size >> 2;

    const size_t pairs_b  = (size_t)P1B * IPB * sizeof(uint2);     // 64 MiB
    const size_t table_b  = (size_t)P1B * NB * sizeof(unsigned);   //  8 MiB
    const size_t need = pairs_b + 2 * table_b;                     // 80 MiB
    if (ws_size >= need && out_size == NB * RB && n == P1B * IPB) {
        uint2* pairs = (uint2*)d_ws;
        unsigned* tableA = (unsigned*)((char*)d_ws + pairs_b);
        unsigned* tableB = (unsigned*)((char*)d_ws + pairs_b + table_b);

        partition_kernel<<<P1B, 256, 0, stream>>>(
            (const float4*)updates, (const int4*)mask, tableA, pairs);
        transpose_kernel<<<dim3(NB / 32, P1B / 32), 256, 0, stream>>>(tableA, tableB);
        unbin_kernel<<<NB, 256, RB * sizeof(float), stream>>>(
            tableB, pairs, (float4*)out);
    } else {
        zero_out_kernel<<<(o4 + 255) / 256, 256, 0, stream>>>((float4*)out, o4);
        scatter_add_kernel<<<(n4 + 255) / 256, 256, 0, stream>>>(
            (const float4*)updates, (const int4*)mask, out, n4);
    }
}

// Round 5
// 256.947 us; speedup vs baseline: 1.1613x; 1.1613x over previous
//
#include <hip/hip_runtime.h>

// MaxUnpooling2D scatter-add: out[mask[i]] += updates[i]
//   n = 8,388,608 updates (fp32) + indices (int32), out_size = 33,554,432 fp32 (134 MB).
//
// v5: partition (block-local counting sort, coalesced dump) + table transpose
//     unchanged. Unbin = per-thread walk of 4 chunks INTERLEAVED (4 independent
//     loads in flight), uint4 double-pair loads with boundary predication, and
//     XCD-swizzled bucket order so adjacent buckets' pair lines hit one L2.

#define NB        2048          // buckets; bucket = idx >> 14
#define NB_SHIFT  14
#define RB        16384         // floats per bucket output region (64 KB)
#define P1B       1024          // partition blocks
#define IPB       8192          // items per partition block (= n / P1B)

__global__ __launch_bounds__(256) void partition_kernel(
        const float4* __restrict__ upd4,
        const int4*   __restrict__ mask4,
        unsigned int* __restrict__ tableA,   // [P1B][NB] packed: start | cnt<<16
        uint2*        __restrict__ pairs) {  // [P1B][IPB]
    __shared__ unsigned int hb[NB];      // hist -> base/cursor
    __shared__ unsigned int tsum[256];
    __shared__ uint2 stage[IPB];         // 64 KB
    const int t = threadIdx.x;
    const int k = blockIdx.x;
    const int s4 = k * (IPB / 4);

    for (int b = t; b < NB; b += 256) hb[b] = 0u;
    __syncthreads();

    int4 mm[IPB / 4 / 256];
    #pragma unroll
    for (int j = 0; j < IPB / 4 / 256; ++j) mm[j] = mask4[s4 + j * 256 + t];
    #pragma unroll
    for (int j = 0; j < IPB / 4 / 256; ++j) {
        atomicAdd(&hb[((unsigned)mm[j].x) >> NB_SHIFT], 1u);
        atomicAdd(&hb[((unsigned)mm[j].y) >> NB_SHIFT], 1u);
        atomicAdd(&hb[((unsigned)mm[j].z) >> NB_SHIFT], 1u);
        atomicAdd(&hb[((unsigned)mm[j].w) >> NB_SHIFT], 1u);
    }
    __syncthreads();

    // Block-wide exclusive scan of hb[NB]
    unsigned c[8], s = 0;
    #pragma unroll
    for (int j = 0; j < 8; ++j) { c[j] = hb[t * 8 + j]; s += c[j]; }
    tsum[t] = s;
    __syncthreads();
    #pragma unroll
    for (int d = 1; d < 256; d <<= 1) {
        unsigned v = (t >= d) ? tsum[t - d] : 0u;
        __syncthreads();
        tsum[t] += v;
        __syncthreads();
    }
    unsigned run = (t > 0) ? tsum[t - 1] : 0u;
    #pragma unroll
    for (int j = 0; j < 8; ++j) {
        unsigned b = t * 8 + j;
        hb[b] = run;
        tableA[(size_t)k * NB + b] = run | (c[j] << 16);
        run += c[j];
    }
    __syncthreads();

    float4 uu[IPB / 4 / 256];
    #pragma unroll
    for (int j = 0; j < IPB / 4 / 256; ++j) uu[j] = upd4[s4 + j * 256 + t];
    #pragma unroll
    for (int j = 0; j < IPB / 4 / 256; ++j) {
        #define PLACE(mi, vi) { \
            unsigned b_ = ((unsigned)(mi)) >> NB_SHIFT; \
            unsigned pos_ = atomicAdd(&hb[b_], 1u); \
            stage[pos_] = make_uint2(((unsigned)(mi)) & (RB - 1u), __float_as_uint(vi)); }
        PLACE(mm[j].x, uu[j].x)
        PLACE(mm[j].y, uu[j].y)
        PLACE(mm[j].z, uu[j].z)
        PLACE(mm[j].w, uu[j].w)
        #undef PLACE
    }
    __syncthreads();

    const uint4* sp = (const uint4*)stage;
    uint4* dp = (uint4*)(pairs + (size_t)k * IPB);
    #pragma unroll
    for (int j = 0; j < IPB / 2 / 256; ++j) dp[j * 256 + t] = sp[j * 256 + t];
}

// tableA [P1B][NB] -> tableB [NB][P1B] so unbin reads its row coalesced.
__global__ __launch_bounds__(256) void transpose_kernel(
        const unsigned int* __restrict__ A, unsigned int* __restrict__ B) {
    __shared__ unsigned int tile[32][33];
    const int tx = threadIdx.x & 31, ty = threadIdx.x >> 5;
    const int bx = blockIdx.x;
    const int by = blockIdx.y;
    #pragma unroll
    for (int r = 0; r < 32; r += 8)
        tile[ty + r][tx] = A[(size_t)(by * 32 + ty + r) * NB + bx * 32 + tx];
    __syncthreads();
    #pragma unroll
    for (int r = 0; r < 32; r += 8)
        B[(size_t)(bx * 32 + ty + r) * P1B + by * 32 + tx] = tile[tx][ty + r];
}

__global__ __launch_bounds__(256) void unbin_kernel(
        const unsigned int* __restrict__ tableB,  // [NB][P1B]
        const uint2*        __restrict__ pairs,
        float4*             __restrict__ out4) {
    __shared__ float tile[RB];          // 64 KB static
    const int t = threadIdx.x;
    // XCD swizzle: XCD x processes buckets [x*256, x*256+256) in order,
    // so adjacent buckets' pair-lines are reused within one L2.
    const int b = ((blockIdx.x & 7) << 8) | (blockIdx.x >> 3);
    float4* t4 = (float4*)tile;

    for (int j = t; j < RB / 4; j += 256) t4[j] = make_float4(0.f, 0.f, 0.f, 0.f);

    // Coalesced descriptor read: 4 chunks per thread (blocks 4t..4t+3)
    uint4 e = ((const uint4*)(tableB + (size_t)b * P1B))[t];
    unsigned s0 = (unsigned)(t * 4 + 0) * IPB + (e.x & 0xFFFFu), e0 = s0 + (e.x >> 16);
    unsigned s1 = (unsigned)(t * 4 + 1) * IPB + (e.y & 0xFFFFu), e1 = s1 + (e.y >> 16);
    unsigned s2 = (unsigned)(t * 4 + 2) * IPB + (e.z & 0xFFFFu), e2 = s2 + (e.z >> 16);
    unsigned s3 = (unsigned)(t * 4 + 3) * IPB + (e.w & 0xFFFFu), e3 = s3 + (e.w >> 16);
    unsigned a0 = s0 & ~1u, a1 = s1 & ~1u, a2 = s2 & ~1u, a3 = s3 & ~1u;
    __syncthreads();   // tile zeroed

    const uint4* p4 = (const uint4*)pairs;
    while ((a0 < e0) | (a1 < e1) | (a2 < e2) | (a3 < e3)) {
        bool c0 = a0 < e0, c1 = a1 < e1, c2 = a2 < e2, c3 = a3 < e3;
        uint4 v0, v1, v2, v3;
        if (c0) v0 = p4[a0 >> 1];       // pairs a0, a0+1 (a0 even -> 16B aligned)
        if (c1) v1 = p4[a1 >> 1];
        if (c2) v2 = p4[a2 >> 1];
        if (c3) v3 = p4[a3 >> 1];
        if (c0) {
            if (a0 >= s0)     atomicAdd(&tile[v0.x], __uint_as_float(v0.y));
            if (a0 + 1 < e0)  atomicAdd(&tile[v0.z], __uint_as_float(v0.w));
            a0 += 2;
        }
        if (c1) {
            if (a1 >= s1)     atomicAdd(&tile[v1.x], __uint_as_float(v1.y));
            if (a1 + 1 < e1)  atomicAdd(&tile[v1.z], __uint_as_float(v1.w));
            a1 += 2;
        }
        if (c2) {
            if (a2 >= s2)     atomicAdd(&tile[v2.x], __uint_as_float(v2.y));
            if (a2 + 1 < e2)  atomicAdd(&tile[v2.z], __uint_as_float(v2.w));
            a2 += 2;
        }
        if (c3) {
            if (a3 >= s3)     atomicAdd(&tile[v3.x], __uint_as_float(v3.y));
            if (a3 + 1 < e3)  atomicAdd(&tile[v3.z], __uint_as_float(v3.w));
            a3 += 2;
        }
    }
    __syncthreads();

    for (int j = t; j < RB / 4; j += 256)
        out4[(size_t)b * (RB / 4) + j] = t4[j];
}

// ---- fallback (direct atomics) if workspace/shape unexpected ----
__global__ void zero_out_kernel(float4* __restrict__ out, int n4) {
    int i = blockIdx.x * blockDim.x + threadIdx.x;
    if (i < n4) out[i] = make_float4(0.f, 0.f, 0.f, 0.f);
}
__global__ void scatter_add_kernel(const float4* __restrict__ upd,
                                   const int4* __restrict__ mask,
                                   float* __restrict__ out, int n4) {
    int i = blockIdx.x * blockDim.x + threadIdx.x;
    if (i < n4) {
        float4 u = upd[i];
        int4 m = mask[i];
        atomicAdd(out + m.x, u.x);
        atomicAdd(out + m.y, u.y);
        atomicAdd(out + m.z, u.z);
        atomicAdd(out + m.w, u.w);
    }
}

extern "C" void kernel_launch(void* const* d_in, const int* in_sizes, int n_in,
                              void* d_out, int out_size, void* d_ws, size_t ws_size,
                              hipStream_t stream) {
    const float* updates = (const float*)d_in[0];
    const int*   mask    = (const int*)d_in[1];
    float* out = (float*)d_out;
    const int n  = in_sizes[0];          // 8,388,608
    const int n4 = n >> 2;
    const int o4 = out_size >> 2;

    const size_t pairs_b  = (size_t)P1B * IPB * sizeof(uint2);     // 64 MiB
    const size_t table_b  = (size_t)P1B * NB * sizeof(unsigned);   //  8 MiB
    const size_t need = pairs_b + 2 * table_b;                     // 80 MiB
    if (ws_size >= need && out_size == NB * RB && n == P1B * IPB) {
        uint2* pairs = (uint2*)d_ws;
        unsigned* tableA = (unsigned*)((char*)d_ws + pairs_b);
        unsigned* tableB = (unsigned*)((char*)d_ws + pairs_b + table_b);

        partition_kernel<<<P1B, 256, 0, stream>>>(
            (const float4*)updates, (const int4*)mask, tableA, pairs);
        transpose_kernel<<<dim3(NB / 32, P1B / 32), 256, 0, stream>>>(tableA, tableB);
        unbin_kernel<<<NB, 256, 0, stream>>>(tableB, pairs, (float4*)out);
    } else {
        zero_out_kernel<<<(o4 + 255) / 256, 256, 0, stream>>>((float4*)out, o4);
        scatter_add_kernel<<<(n4 + 255) / 256, 256, 0, stream>>>(
            (const float4*)updates, (const int4*)mask, out, n4);
    }
}